// Round 14
// baseline (69.264 us; speedup 1.0000x reference)
//
#include <hip/hip_runtime.h>
#include <math.h>

typedef short short8 __attribute__((ext_vector_type(8)));
typedef float f32x4 __attribute__((ext_vector_type(4)));

#define B_N 2048
#define NKM 9
#define CP 512          // C*4, cp = c*4 + p  (p fastest)
#define KU 128          // MUL
#define STG 68          // stage row stride (ushorts) for 64-col tile
#define INV_SQRT_MUL 0.08838834764831845f   // 1/sqrt(128)
#define INV_SQRT_4C  0.04419417382415922f   // 1/sqrt(512)

// persistent device scratch; fully rewritten every launch before any read
__device__ ushort g_xb1[NKM * B_N * KU];          // [km][b][u] bf16
__device__ ushort g_xb2[NKM * B_N * KU];
__device__ ushort g_W1bt[3 * CP * KU];            // [l][cp][u] bf16, * 1/sqrt(128)
__device__ ushort g_W2bt[3 * CP * KU];
__device__ ushort g_Woutbt[3 * KU * CP];          // [l][u][cp] bf16, * 1/sqrt(512)
__device__ ushort g_cb[(size_t)B_N * NKM * CP];   // c_out, [b][km][cp] bf16

__device__ __forceinline__ ushort f2b(float f) {
    uint u = __float_as_uint(f);
    uint r = (u + 0x7fffu + ((u >> 16) & 1u)) >> 16;   // RNE
    return (ushort)r;
}
__device__ __forceinline__ float pk_lo(uint u) { return __uint_as_float(u << 16); }
__device__ __forceinline__ float pk_hi(uint u) { return __uint_as_float(u & 0xffff0000u); }
__device__ __forceinline__ int l_of_km(int km) { return (km >= 4) ? 2 : (km >= 1 ? 1 : 0); }

// ---------------------------------------------------------------------------
// Gaunt tensor (real orthonormal SH, l<=2): closed form; per-i constexpr
// sub-tables -> constexpr loop bounds -> full unroll -> literal reg indices.
// ---------------------------------------------------------------------------
__host__ __device__ constexpr int lof(int n) { return n >= 4 ? 2 : (n >= 1 ? 1 : 0); }
__host__ __device__ constexpr int mof(int n) { int l = lof(n); return n - l * l - l; }
__host__ __device__ constexpr bool gaunt_nz(int a, int b, int c) {
    int la = lof(a), lb = lof(b), lc = lof(c);
    if ((la + lb + lc) & 1) return false;
    if (lc > la + lb || la > lb + lc || lb > lc + la) return false;
    int ma = mof(a), mb = mof(b), mc = mof(c);
    int neg = (ma < 0) + (mb < 0) + (mc < 0);
    if (neg & 1) return false;
    int A = ma < 0 ? -ma : ma, Bm = mb < 0 ? -mb : mb, Cm = mc < 0 ? -mc : mc;
    return (A + Bm == Cm) || (Bm + Cm == A) || (Cm + A == Bm);
}
__host__ __device__ constexpr float gaunt_val(int a, int b, int c) {
    int x = a, y = b, z = c, t = 0;
    if (x > y) { t = x; x = y; y = t; }
    if (y > z) { t = y; y = z; z = t; }
    if (x > y) { t = x; x = y; y = t; }
    const float C00 = 0.28209479177387814f;   // 1/(2*sqrt(pi))
    const float A_  = 0.12615662610100802f;
    const float B_  = 0.25231325220201604f;
    const float C_  = 0.21850968611841584f;
    const float D_  = 0.18022375157286857f;
    const float E_  = 0.09011187578643429f;
    const float F_  = 0.15607834722743988f;
    if (x == 0) return C00;
    if (y <= 3) {
        if (z == 6) return (y == 2) ? B_ : -A_;
        if (z == 8) return (x == 1) ? -C_ : C_;
        return C_;
    }
    if (x == 4) return (y == 4) ? -D_ : F_;
    if (x == 5) return (z == 6) ? E_ : -F_;
    if (x == 6) return (y == 6) ? D_ : ((y == 7) ? E_ : -D_);
    return F_;
}
struct IEnt { int k, j; float v; };
struct ITab { IEnt e[16]; int n; };
__host__ __device__ constexpr ITab make_it(int ii) {
    ITab t{};
    for (int k = 0; k < 9; ++k)
        for (int j = 0; j < 9; ++j)
            if (gaunt_nz(k, ii, j)) {
                t.e[t.n].k = k; t.e[t.n].j = j; t.e[t.n].v = gaunt_val(k, ii, j);
                ++t.n;
            }
    return t;
}

// per-km middle step (single unit): accumulate i-plane's Gaunt terms into o
template <int I>
__device__ __forceinline__ void mid_step(const ushort* __restrict__ c1s,
                                         int mb, int mc,
                                         const float (&f2v)[9][4],
                                         float (&o)[4][9]) {
    constexpr ITab T = make_it(I);
    uint2 v = *(const uint2*)&c1s[mb * STG + mc * 4];
    float a0 = pk_lo(v.x), a1 = pk_hi(v.x);
    float a2 = pk_lo(v.y), a3 = pk_hi(v.y);
    #pragma unroll
    for (int e = 0; e < T.n; ++e) {          // constexpr bound -> full unroll
        const int   k = T.e[e].k, j = T.e[e].j;
        const float g = T.e[e].v;
        float d0 = f2v[j][0], d1 = f2v[j][1];
        float d2 = f2v[j][2], d3 = f2v[j][3];
        o[0][k] = fmaf(g, a0 * d0, o[0][k]);
        o[1][k] = fmaf(g, fmaf(a2, d3, -(a3 * d2)), o[1][k]);
        o[2][k] = fmaf(g, fmaf(a3, d1, -(a1 * d3)), o[2][k]);
        o[3][k] = fmaf(g, fmaf(a1, d2, -(a2 * d1)), o[3][k]);
    }
}

// ---------------------------------------------------------------------------
// prep_combined (unchanged, validated)
// ---------------------------------------------------------------------------
__global__ __launch_bounds__(256) void prep_kernel(const float* __restrict__ x1,
                                                   const float* __restrict__ x2,
                                                   const float* __restrict__ W1,
                                                   const float* __restrict__ W2,
                                                   const float* __restrict__ Wout,
                                                   float* __restrict__ out) {
    int bid = blockIdx.x, tid = threadIdx.x;
    if (bid >= B_N) {
        int idx = (bid - B_N) * 256 + tid;       // < 3*512*128 = 196608
        int l = idx >> 16;
        int r = idx & 65535;
        {   // W1bt/W2bt [l][cp][u] <- W[l][u][cp]
            int cp = r >> 7, u = r & 127;
            size_t src = (size_t)l * 65536 + (size_t)u * 512 + cp;
            g_W1bt[idx] = f2b(W1[src] * INV_SQRT_MUL);
            g_W2bt[idx] = f2b(W2[src] * INV_SQRT_MUL);
        }
        {   // Woutbt [l][u][cp] <- Wout[l][cp][u]
            int u = r >> 9, cp = r & 511;
            g_Woutbt[idx] = f2b(Wout[(size_t)l * 65536 + (size_t)cp * 128 + u] * INV_SQRT_4C);
        }
        return;
    }
    int b = bid;
    __shared__ float L1[2048], L2[2048];
    const float4* r1 = (const float4*)(x1 + (size_t)b * 2048);
    const float4* r2 = (const float4*)(x2 + (size_t)b * 2048);
    #pragma unroll
    for (int i = 0; i < 2; ++i) {
        int q = i * 256 + tid;
        *(float4*)&L1[q * 4] = r1[q];
        *(float4*)&L2[q * 4] = r2[q];
    }
    float4 z = make_float4(0.f, 0.f, 0.f, 0.f);
    if (tid < 224) *(float4*)&out[(size_t)b * 2048 + 1152 + tid * 4] = z;
    __syncthreads();
    #pragma unroll
    for (int i = 0; i < 9; ++i) {
        int e = i * 256 + tid;                    // < 2304
        int field = e >= 1152;
        int r = e - field * 1152;
        int km = r >> 7, u = r & 127;
        int l = l_of_km(km);
        int col = l * l * 128 + u * (2 * l + 1) + (km - l * l);
        float v = field ? L2[col] : L1[col];
        ushort* dst = field ? g_xb2 : g_xb1;
        dst[(size_t)km * (B_N * KU) + (size_t)b * KU + u] = f2b(v);
    }
}

// ---------------------------------------------------------------------------
// cmid v2 helpers
// ---------------------------------------------------------------------------
__device__ __forceinline__ void load_B64(const ushort* __restrict__ wb, int n0,
                                         int tid, ushort* Bs) {
    #pragma unroll
    for (int it = 0; it < 4; ++it) {           // 1024 16B chunks (64 rows x 16)
        int i = it * 256 + tid;
        int row = i >> 4, kg = i & 15;
        int dst = row * 128 + ((kg ^ (row & 7)) << 3);
        *(short8*)&Bs[dst] = *(const short8*)&wb[(size_t)(n0 + row) * KU + (kg << 3)];
    }
}
__device__ __forceinline__ void gemm16x64(const ushort* As_, const ushort* Bs_,
                                          int lane, int wid, ushort* stage) {
    f32x4 acc = (f32x4){0.f, 0.f, 0.f, 0.f};
    #pragma unroll
    for (int ks = 0; ks < 4; ++ks) {
        int kg = ks * 4 + (lane >> 4);
        int ar = lane & 15;
        short8 a = *(const short8*)&As_[ar * 128 + ((kg ^ (ar & 7)) << 3)];
        int br = wid * 16 + (lane & 15);
        short8 b = *(const short8*)&Bs_[br * 128 + ((kg ^ (br & 7)) << 3)];
        acc = __builtin_amdgcn_mfma_f32_16x16x32_bf16(a, b, acc, 0, 0, 0);
    }
    #pragma unroll
    for (int r = 0; r < 4; ++r) {
        int row = ((lane >> 4) << 2) + r;       // b-row 0..15
        stage[row * STG + wid * 16 + (lane & 15)] = f2b(acc[r]);
    }
}

// one fused step: barrier; prefetch next A (global->reg); GEMM; barrier;
// A reg->LDS (alt buf); consume stage (f2v extract or mid_step); optional B load
template <int S>
__device__ __forceinline__ void cmid_step(int b0, int n0, int tid, int lane, int wid,
                                          int mb, int mc,
                                          ushort* As0, ushort* As1,
                                          ushort* Bs, ushort* stage,
                                          float (&f2v)[9][4], float (&o)[4][9]) {
    constexpr int fld  = (S < 9) ? 2 : 1;
    constexpr int km   = S % 9;
    constexpr bool hasNext = (S < 17);
    constexpr int Sn   = hasNext ? S + 1 : S;
    constexpr int nfld = (Sn < 9) ? 2 : 1;
    constexpr int nkm  = Sn % 9;
    constexpr int nl   = (nkm >= 4) ? 2 : (nkm >= 1 ? 1 : 0);
    constexpr int cl   = (km  >= 4) ? 2 : (km  >= 1 ? 1 : 0);
    constexpr bool newB = hasNext && (nl != cl || nfld != fld);

    ushort* Acur = (S & 1) ? As1 : As0;
    ushort* Anxt = (S & 1) ? As0 : As1;

    __syncthreads();                           // As(cur), Bs ready; stage free
    int arow = tid >> 4, akg = tid & 15;
    short8 av;
    if constexpr (hasNext) {                   // issue early: hides under GEMM
        const ushort* xsrc = (nfld == 2 ? g_xb2 : g_xb1) + (size_t)nkm * (B_N * KU);
        av = *(const short8*)&xsrc[(size_t)(b0 + arow) * KU + (akg << 3)];
    }
    gemm16x64(Acur, Bs, lane, wid, stage);
    __syncthreads();                           // stage visible; As(nxt)/Bs free
    if constexpr (hasNext)
        *(short8*)&Anxt[arow * 128 + ((akg ^ (arow & 7)) << 3)] = av;
    if constexpr (fld == 2) {
        uint2 v = *(const uint2*)&stage[mb * STG + mc * 4];
        f2v[km][0] = pk_lo(v.x); f2v[km][1] = pk_hi(v.x);
        f2v[km][2] = pk_lo(v.y); f2v[km][3] = pk_hi(v.y);
    } else {
        mid_step<km>(stage, mb, mc, f2v, o);
    }
    if constexpr (newB) {
        const ushort* wsrc = (nfld == 2 ? g_W2bt : g_W1bt) + (size_t)nl * 65536;
        load_B64(wsrc, n0, tid, Bs);
    }
}

// ---------------------------------------------------------------------------
// cmid v2: fused stage-1 GEMMs + Gaunt middle. Block = 16 b-rows x 64 cp,
// 256 thr. ~27 KB LDS -> 4 blocks/CU resident (grid 1024) = 16 waves/CU.
// A double-buffered + prefetched; c2 extracted to regs per-km (no big c2s).
// Writes only g_cb.  grid (8 cp-tiles, 128 b-tiles).
// ---------------------------------------------------------------------------
__global__ __launch_bounds__(256) void cmid_kernel() {
    __shared__ ushort As0[16 * 128];       // 4 KB
    __shared__ ushort As1[16 * 128];       // 4 KB
    __shared__ ushort Bs[64 * 128];        // 16 KB
    __shared__ ushort stage[16 * STG];     // 2.2 KB

    int tid = threadIdx.x;
    int n0 = blockIdx.x * 64, b0 = blockIdx.y * 16;
    int lane = tid & 63, wid = tid >> 6;
    int mb = tid >> 4, mc = tid & 15;      // middle unit: (b = b0+mb, c-slot mc)

    // prologue: B(l=0, field2) + A(km=0, field2) -> As0
    load_B64(g_W2bt, n0, tid, Bs);
    {
        int arow = tid >> 4, akg = tid & 15;
        *(short8*)&As0[arow * 128 + ((akg ^ (arow & 7)) << 3)] =
            *(const short8*)&g_xb2[(size_t)(b0 + arow) * KU + (akg << 3)];
    }

    float f2v[9][4];
    float o[4][9];
    #pragma unroll
    for (int p = 0; p < 4; ++p)
        #pragma unroll
        for (int k = 0; k < 9; ++k) o[p][k] = 0.f;

    cmid_step<0>(b0, n0, tid, lane, wid, mb, mc, As0, As1, Bs, stage, f2v, o);
    cmid_step<1>(b0, n0, tid, lane, wid, mb, mc, As0, As1, Bs, stage, f2v, o);
    cmid_step<2>(b0, n0, tid, lane, wid, mb, mc, As0, As1, Bs, stage, f2v, o);
    cmid_step<3>(b0, n0, tid, lane, wid, mb, mc, As0, As1, Bs, stage, f2v, o);
    cmid_step<4>(b0, n0, tid, lane, wid, mb, mc, As0, As1, Bs, stage, f2v, o);
    cmid_step<5>(b0, n0, tid, lane, wid, mb, mc, As0, As1, Bs, stage, f2v, o);
    cmid_step<6>(b0, n0, tid, lane, wid, mb, mc, As0, As1, Bs, stage, f2v, o);
    cmid_step<7>(b0, n0, tid, lane, wid, mb, mc, As0, As1, Bs, stage, f2v, o);
    cmid_step<8>(b0, n0, tid, lane, wid, mb, mc, As0, As1, Bs, stage, f2v, o);
    cmid_step<9>(b0, n0, tid, lane, wid, mb, mc, As0, As1, Bs, stage, f2v, o);
    cmid_step<10>(b0, n0, tid, lane, wid, mb, mc, As0, As1, Bs, stage, f2v, o);
    cmid_step<11>(b0, n0, tid, lane, wid, mb, mc, As0, As1, Bs, stage, f2v, o);
    cmid_step<12>(b0, n0, tid, lane, wid, mb, mc, As0, As1, Bs, stage, f2v, o);
    cmid_step<13>(b0, n0, tid, lane, wid, mb, mc, As0, As1, Bs, stage, f2v, o);
    cmid_step<14>(b0, n0, tid, lane, wid, mb, mc, As0, As1, Bs, stage, f2v, o);
    cmid_step<15>(b0, n0, tid, lane, wid, mb, mc, As0, As1, Bs, stage, f2v, o);
    cmid_step<16>(b0, n0, tid, lane, wid, mb, mc, As0, As1, Bs, stage, f2v, o);
    cmid_step<17>(b0, n0, tid, lane, wid, mb, mc, As0, As1, Bs, stage, f2v, o);

    // write cb: 9 x 8B coalesced stores (unit's 4 p-values per km)
    ushort* w = g_cb + (size_t)(b0 + mb) * (NKM * CP) + n0 + mc * 4;
    #pragma unroll
    for (int k = 0; k < 9; ++k) {
        uint2 st;
        st.x = (uint)f2b(o[0][k]) | ((uint)f2b(o[1][k]) << 16);
        st.y = (uint)f2b(o[2][k]) | ((uint)f2b(o[3][k]) << 16);
        *(uint2*)&w[(size_t)k * CP] = st;
    }
}

// ---------------------------------------------------------------------------
// out_gemm (unchanged, validated): out = cb x Woutbt, 64x128 tile, K=512
// ---------------------------------------------------------------------------
__global__ __launch_bounds__(256) void out_gemm_kernel(float* __restrict__ out) {
    __shared__ ushort Aso[64 * 128];
    __shared__ ushort Bso[128 * 128];
    int tid = threadIdx.x;
    int km = blockIdx.y;
    int l = l_of_km(km);
    int mi = km - l * l, d = 2 * l + 1, OFF = 128 * l * l;
    int b0 = blockIdx.x * 64;

    int lane = tid & 63, wid = tid >> 6, wr = wid >> 1, wc = wid & 1;
    f32x4 acc[2][4];
    #pragma unroll
    for (int i = 0; i < 2; ++i)
        #pragma unroll
        for (int j = 0; j < 4; ++j) acc[i][j] = (f32x4){0.f, 0.f, 0.f, 0.f};

    for (int kc = 0; kc < 4; ++kc) {
        #pragma unroll
        for (int it = 0; it < 4; ++it) {
            int i = it * 256 + tid;
            int row = i >> 4, kg = i & 15;
            int dst = row * 128 + ((kg ^ (row & 7)) << 3);
            *(short8*)&Aso[dst] = *(const short8*)&g_cb[(size_t)(b0 + row) * (NKM * CP)
                                                       + (size_t)km * CP + kc * 128 + (kg << 3)];
        }
        #pragma unroll
        for (int it = 0; it < 8; ++it) {
            int i = it * 256 + tid;
            int row = i >> 4, kg = i & 15;
            int dst = row * 128 + ((kg ^ (row & 7)) << 3);
            *(short8*)&Bso[dst] = *(const short8*)&g_Woutbt[(size_t)l * 65536
                                                       + (size_t)row * CP + kc * 128 + (kg << 3)];
        }
        __syncthreads();
        #pragma unroll
        for (int ks = 0; ks < 4; ++ks) {
            int kg = ks * 4 + (lane >> 4);
            short8 a[2], b[4];
            #pragma unroll
            for (int i = 0; i < 2; ++i) {
                int row = wr * 32 + i * 16 + (lane & 15);
                a[i] = *(const short8*)&Aso[row * 128 + ((kg ^ (row & 7)) << 3)];
            }
            #pragma unroll
            for (int j = 0; j < 4; ++j) {
                int row = wc * 64 + j * 16 + (lane & 15);
                b[j] = *(const short8*)&Bso[row * 128 + ((kg ^ (row & 7)) << 3)];
            }
            #pragma unroll
            for (int i = 0; i < 2; ++i)
                #pragma unroll
                for (int j = 0; j < 4; ++j)
                    acc[i][j] = __builtin_amdgcn_mfma_f32_16x16x32_bf16(a[i], b[j], acc[i][j], 0, 0, 0);
        }
        __syncthreads();
    }

    #pragma unroll
    for (int i = 0; i < 2; ++i)
        #pragma unroll
        for (int j = 0; j < 4; ++j)
            #pragma unroll
            for (int r = 0; r < 4; ++r) {
                int row = b0 + wr * 32 + i * 16 + ((lane >> 4) << 2) + r;
                int u   = wc * 64 + j * 16 + (lane & 15);
                out[(size_t)row * 2048 + OFF + u * d + mi] = acc[i][j][r];
            }
}

// ---------------------------------------------------------------------------
extern "C" void kernel_launch(void* const* d_in, const int* in_sizes, int n_in,
                              void* d_out, int out_size, void* d_ws, size_t ws_size,
                              hipStream_t stream) {
    const float* x1   = (const float*)d_in[0];
    const float* x2   = (const float*)d_in[1];
    const float* W1   = (const float*)d_in[2];
    const float* W2   = (const float*)d_in[3];
    const float* Wout = (const float*)d_in[4];
    float* out = (float*)d_out;

    prep_kernel<<<B_N + 768, 256, 0, stream>>>(x1, x2, W1, W2, Wout, out);
    cmid_kernel<<<dim3(CP / 64, B_N / 16), 256, 0, stream>>>();
    out_gemm_kernel<<<dim3(B_N / 64, NKM), 256, 0, stream>>>(out);
}

// Round 15
// 55.653 us; speedup vs baseline: 1.2446x; 1.2446x over previous
//
#include <hip/hip_runtime.h>
#include <math.h>

typedef short short8 __attribute__((ext_vector_type(8)));
typedef float f32x4 __attribute__((ext_vector_type(4)));

#define B_N 2048
#define NKM 9
#define CP 512          // C*4, cp = c*4 + p  (p fastest)
#define KU 128          // MUL
#define INV_SQRT_MUL 0.08838834764831845f   // 1/sqrt(128)
#define INV_SQRT_4C  0.04419417382415922f   // 1/sqrt(512)

// persistent device scratch; fully rewritten every launch before any read
__device__ ushort g_xb1[NKM * B_N * KU];          // [km][b][u] bf16
__device__ ushort g_xb2[NKM * B_N * KU];
__device__ ushort g_W1bt[3 * CP * KU];            // [l][cp][u] bf16, * 1/sqrt(128)
__device__ ushort g_W2bt[3 * CP * KU];
__device__ ushort g_Woutbt[3 * KU * CP];          // [l][u][cp] bf16, * 1/sqrt(512)
__device__ ushort g_c1b[(size_t)B_N * NKM * CP];  // [b][km][cp] bf16
__device__ ushort g_c2b[(size_t)B_N * NKM * CP];
__device__ ushort g_cb[(size_t)B_N * NKM * CP];   // c_out, [b][km][cp] bf16

__device__ __forceinline__ ushort f2b(float f) {
    uint u = __float_as_uint(f);
    uint r = (u + 0x7fffu + ((u >> 16) & 1u)) >> 16;   // RNE
    return (ushort)r;
}
__device__ __forceinline__ float pk_lo(uint u) { return __uint_as_float(u << 16); }
__device__ __forceinline__ float pk_hi(uint u) { return __uint_as_float(u & 0xffff0000u); }
__device__ __forceinline__ int l_of_km(int km) { return (km >= 4) ? 2 : (km >= 1 ? 1 : 0); }

// ---------------------------------------------------------------------------
// Gaunt tensor (real orthonormal SH, l<=2): closed form; per-k constexpr
// sub-tables -> constexpr loop bounds -> full unroll -> literal reg indices.
// ---------------------------------------------------------------------------
__host__ __device__ constexpr int lof(int n) { return n >= 4 ? 2 : (n >= 1 ? 1 : 0); }
__host__ __device__ constexpr int mof(int n) { int l = lof(n); return n - l * l - l; }
__host__ __device__ constexpr bool gaunt_nz(int a, int b, int c) {
    int la = lof(a), lb = lof(b), lc = lof(c);
    if ((la + lb + lc) & 1) return false;
    if (lc > la + lb || la > lb + lc || lb > lc + la) return false;
    int ma = mof(a), mb = mof(b), mc = mof(c);
    int neg = (ma < 0) + (mb < 0) + (mc < 0);
    if (neg & 1) return false;
    int A = ma < 0 ? -ma : ma, Bm = mb < 0 ? -mb : mb, Cm = mc < 0 ? -mc : mc;
    return (A + Bm == Cm) || (Bm + Cm == A) || (Cm + A == Bm);
}
__host__ __device__ constexpr float gaunt_val(int a, int b, int c) {
    int x = a, y = b, z = c, t = 0;
    if (x > y) { t = x; x = y; y = t; }
    if (y > z) { t = y; y = z; z = t; }
    if (x > y) { t = x; x = y; y = t; }
    const float C00 = 0.28209479177387814f;   // 1/(2*sqrt(pi))
    const float A_  = 0.12615662610100802f;
    const float B_  = 0.25231325220201604f;
    const float C_  = 0.21850968611841584f;
    const float D_  = 0.18022375157286857f;
    const float E_  = 0.09011187578643429f;
    const float F_  = 0.15607834722743988f;
    if (x == 0) return C00;
    if (y <= 3) {
        if (z == 6) return (y == 2) ? B_ : -A_;
        if (z == 8) return (x == 1) ? -C_ : C_;
        return C_;
    }
    if (x == 4) return (y == 4) ? -D_ : F_;
    if (x == 5) return (z == 6) ? E_ : -F_;
    if (x == 6) return (y == 6) ? D_ : ((y == 7) ? E_ : -D_);
    return F_;
}
struct KEnt { int i, j; float v; };
struct KTab { KEnt e[16]; int n; };
__host__ __device__ constexpr KTab make_kt(int kk) {
    KTab t{};
    for (int i = 0; i < 9; ++i)
        for (int j = 0; j < 9; ++j)
            if (gaunt_nz(kk, i, j)) {
                t.e[t.n].i = i; t.e[t.n].j = j; t.e[t.n].v = gaunt_val(kk, i, j);
                ++t.n;
            }
    return t;
}

template <int KK>
__device__ __forceinline__ void gaunt_kk(const uint (&p1)[2][9], const uint (&p2)[2][9],
                                         ushort* __restrict__ w) {
    constexpr KTab T = make_kt(KK);
    float o0 = 0.f, o1 = 0.f, o2 = 0.f, o3 = 0.f;
    #pragma unroll
    for (int e = 0; e < T.n; ++e) {        // constexpr bound -> full unroll
        const int   i = T.e[e].i, j = T.e[e].j;
        const float g = T.e[e].v;
        float a0 = pk_lo(p1[0][i]), a1 = pk_hi(p1[0][i]);
        float a2 = pk_lo(p1[1][i]), a3 = pk_hi(p1[1][i]);
        float d0 = pk_lo(p2[0][j]), d1 = pk_hi(p2[0][j]);
        float d2 = pk_lo(p2[1][j]), d3 = pk_hi(p2[1][j]);
        o0 = fmaf(g, a0 * d0, o0);
        o1 = fmaf(g, fmaf(a2, d3, -(a3 * d2)), o1);
        o2 = fmaf(g, fmaf(a3, d1, -(a1 * d3)), o2);
        o3 = fmaf(g, fmaf(a1, d2, -(a2 * d1)), o3);
    }
    uint2 st;
    st.x = (uint)f2b(o0) | ((uint)f2b(o1) << 16);
    st.y = (uint)f2b(o2) | ((uint)f2b(o3) << 16);
    *(uint2*)&w[KK * CP] = st;
}

// ---------------------------------------------------------------------------
// prep_combined (validated):
//   blocks [0, B_N):        x transpose->bf16 for row b, + zero out tail cols
//   blocks [B_N, B_N+768):  W1/W2/Wout bf16 repack with scales folded in
// ---------------------------------------------------------------------------
__global__ __launch_bounds__(256) void prep_kernel(const float* __restrict__ x1,
                                                   const float* __restrict__ x2,
                                                   const float* __restrict__ W1,
                                                   const float* __restrict__ W2,
                                                   const float* __restrict__ Wout,
                                                   float* __restrict__ out) {
    int bid = blockIdx.x, tid = threadIdx.x;
    if (bid >= B_N) {
        int idx = (bid - B_N) * 256 + tid;       // < 3*512*128 = 196608
        int l = idx >> 16;
        int r = idx & 65535;
        {   // W1bt/W2bt [l][cp][u] <- W[l][u][cp]
            int cp = r >> 7, u = r & 127;
            size_t src = (size_t)l * 65536 + (size_t)u * 512 + cp;
            g_W1bt[idx] = f2b(W1[src] * INV_SQRT_MUL);
            g_W2bt[idx] = f2b(W2[src] * INV_SQRT_MUL);
        }
        {   // Woutbt [l][u][cp] <- Wout[l][cp][u]
            int u = r >> 9, cp = r & 511;
            g_Woutbt[idx] = f2b(Wout[(size_t)l * 65536 + (size_t)cp * 128 + u] * INV_SQRT_4C);
        }
        return;
    }
    int b = bid;
    __shared__ float L1[2048], L2[2048];
    const float4* r1 = (const float4*)(x1 + (size_t)b * 2048);
    const float4* r2 = (const float4*)(x2 + (size_t)b * 2048);
    #pragma unroll
    for (int i = 0; i < 2; ++i) {
        int q = i * 256 + tid;
        *(float4*)&L1[q * 4] = r1[q];
        *(float4*)&L2[q * 4] = r2[q];
    }
    // zero the l=3 output tail for this row: cols [1152,2048) = 224 float4
    float4 z = make_float4(0.f, 0.f, 0.f, 0.f);
    if (tid < 224) *(float4*)&out[(size_t)b * 2048 + 1152 + tid * 4] = z;
    __syncthreads();
    #pragma unroll
    for (int i = 0; i < 9; ++i) {
        int e = i * 256 + tid;                    // < 2304
        int field = e >= 1152;
        int r = e - field * 1152;
        int km = r >> 7, u = r & 127;
        int l = l_of_km(km);
        int col = l * l * 128 + u * (2 * l + 1) + (km - l * l);
        float v = field ? L2[col] : L1[col];
        ushort* dst = field ? g_xb2 : g_xb1;
        dst[(size_t)km * (B_N * KU) + (size_t)b * KU + u] = f2b(v);
    }
}

// ---------------------------------------------------------------------------
// gemm_c (r11 64x64 tile, validated) + XCD-chunked swizzle:
// XCD i owns b_tiles [4i, 4i+4) across all 18 z-planes and 8 n-tiles,
// so each XCD's xb slice (1.2 MB) + W (0.8 MB) stays L2-resident.
// 1D grid 4608 = 8 XCD * (4 bt * 18 z * 8 n).
// ---------------------------------------------------------------------------
__global__ __launch_bounds__(256) void gemm_c_kernel() {
    __shared__ ushort As[64 * 128];
    __shared__ ushort Bs[64 * 128];
    int tid = threadIdx.x;
    int bid = blockIdx.x;
    int xcd = bid & 7, slot = bid >> 3;     // slot 0..575
    int btl = slot & 3;
    int rem = slot >> 2;                    // 0..143
    int z  = rem >> 3;                      // 0..17
    int nt = rem & 7;                       // 0..7
    int b0 = (xcd * 4 + btl) * 64, n0 = nt * 64;

    int field = (z >= NKM);
    int km = field ? z - NKM : z;
    int l = l_of_km(km);
    const ushort* xa = (field ? g_xb2 : g_xb1) + (size_t)km * (B_N * KU);
    const ushort* wb = (field ? g_W2bt : g_W1bt) + (size_t)l * 65536;
    ushort* cdst = field ? g_c2b : g_c1b;

    #pragma unroll
    for (int it = 0; it < 4; ++it) {
        int i = it * 256 + tid;            // 16B chunk id, 0..1023
        int row = i >> 4, kg = i & 15;
        int dst = row * 128 + ((kg ^ (row & 7)) << 3);
        *(short8*)&As[dst] = *(const short8*)&xa[(size_t)(b0 + row) * KU + (kg << 3)];
        *(short8*)&Bs[dst] = *(const short8*)&wb[(size_t)(n0 + row) * KU + (kg << 3)];
    }
    __syncthreads();

    int lane = tid & 63, wid = tid >> 6, wr = wid >> 1, wc = wid & 1;
    f32x4 acc[2][2];
    #pragma unroll
    for (int i = 0; i < 2; ++i)
        #pragma unroll
        for (int j = 0; j < 2; ++j) acc[i][j] = (f32x4){0.f, 0.f, 0.f, 0.f};

    #pragma unroll
    for (int ks = 0; ks < 4; ++ks) {
        int kg = ks * 4 + (lane >> 4);
        short8 a[2], b[2];
        #pragma unroll
        for (int i = 0; i < 2; ++i) {
            int row = wr * 32 + i * 16 + (lane & 15);
            a[i] = *(const short8*)&As[row * 128 + ((kg ^ (row & 7)) << 3)];
        }
        #pragma unroll
        for (int j = 0; j < 2; ++j) {
            int row = wc * 32 + j * 16 + (lane & 15);
            b[j] = *(const short8*)&Bs[row * 128 + ((kg ^ (row & 7)) << 3)];
        }
        #pragma unroll
        for (int i = 0; i < 2; ++i)
            #pragma unroll
            for (int j = 0; j < 2; ++j)
                acc[i][j] = __builtin_amdgcn_mfma_f32_16x16x32_bf16(a[i], b[j], acc[i][j], 0, 0, 0);
    }

    #pragma unroll
    for (int i = 0; i < 2; ++i)
        #pragma unroll
        for (int j = 0; j < 2; ++j)
            #pragma unroll
            for (int r = 0; r < 4; ++r) {
                int row = b0 + wr * 32 + i * 16 + ((lane >> 4) << 2) + r;
                int col = n0 + wc * 32 + j * 16 + (lane & 15);
                cdst[((size_t)row * NKM + km) * CP + col] = f2b(acc[i][j][r]);
            }
}

// ---------------------------------------------------------------------------
// middle v8 (validated) + XCD swizzle: XCD i covers b in [256i, 256(i+1))
// -> reads gemm_c's dirty c1/c2 lines on the SAME XCD L2.
// 1D grid 1024; block covers 2 b-rows.
// ---------------------------------------------------------------------------
__global__ __launch_bounds__(256) void middle_kernel() {
    int bid = blockIdx.x;
    int w9 = (bid & 7) * 128 + (bid >> 3);      // bijective: 1024 = 8 * 128
    int idx = w9 * 256 + threadIdx.x;           // < 2048*128
    int b = idx >> 7, c = idx & 127;
    const ushort* s1 = g_c1b + (size_t)b * (NKM * CP) + c * 4;
    const ushort* s2 = g_c2b + (size_t)b * (NKM * CP) + c * 4;

    uint p1[2][9], p2[2][9];
    #pragma unroll
    for (int k = 0; k < 9; ++k) {
        uint2 v1 = *(const uint2*)&s1[k * CP];
        uint2 v2 = *(const uint2*)&s2[k * CP];
        p1[0][k] = v1.x; p1[1][k] = v1.y;
        p2[0][k] = v2.x; p2[1][k] = v2.y;
    }

    ushort* w = g_cb + (size_t)b * (NKM * CP) + c * 4;
    gaunt_kk<0>(p1, p2, w);
    gaunt_kk<1>(p1, p2, w);
    gaunt_kk<2>(p1, p2, w);
    gaunt_kk<3>(p1, p2, w);
    gaunt_kk<4>(p1, p2, w);
    gaunt_kk<5>(p1, p2, w);
    gaunt_kk<6>(p1, p2, w);
    gaunt_kk<7>(p1, p2, w);
    gaunt_kk<8>(p1, p2, w);
}

// ---------------------------------------------------------------------------
// out_gemm (r11 64x64 tile, validated) + XCD swizzle: XCD i owns bx in
// [4i, 4i+4) (matching middle's cb writes -> cb reads are L2-hot) and both
// u-tiles of an A-tile are co-located. 1D grid 576 = 8 * (9 km * 4 bx * 2 u).
// ---------------------------------------------------------------------------
__global__ __launch_bounds__(256) void out_gemm_kernel(float* __restrict__ out) {
    __shared__ ushort As[64 * 128];
    __shared__ ushort Bs[64 * 128];
    int tid = threadIdx.x;
    int bid = blockIdx.x;
    int xcd = bid & 7, s = bid >> 3;        // s 0..71
    int km = s >> 3;                        // 0..8
    int r9 = s & 7;
    int bx = xcd * 4 + (r9 >> 1);
    int by = r9 & 1;

    int l = l_of_km(km);
    int mi = km - l * l, d = 2 * l + 1, OFF = 128 * l * l;
    int b0 = bx * 64, u0 = by * 64;

    int lane = tid & 63, wid = tid >> 6, wr = wid >> 1, wc = wid & 1;
    f32x4 acc[2][2];
    #pragma unroll
    for (int i = 0; i < 2; ++i)
        #pragma unroll
        for (int j = 0; j < 2; ++j) acc[i][j] = (f32x4){0.f, 0.f, 0.f, 0.f};

    for (int kc = 0; kc < 4; ++kc) {
        #pragma unroll
        for (int it = 0; it < 4; ++it) {
            int i = it * 256 + tid;
            int row = i >> 4, kg = i & 15;
            int dst = row * 128 + ((kg ^ (row & 7)) << 3);
            *(short8*)&As[dst] = *(const short8*)&g_cb[(size_t)(b0 + row) * (NKM * CP)
                                                       + (size_t)km * CP + kc * 128 + (kg << 3)];
            *(short8*)&Bs[dst] = *(const short8*)&g_Woutbt[(size_t)l * 65536
                                                       + (size_t)(u0 + row) * CP + kc * 128 + (kg << 3)];
        }
        __syncthreads();
        #pragma unroll
        for (int ks = 0; ks < 4; ++ks) {
            int kg = ks * 4 + (lane >> 4);
            short8 a[2], b[2];
            #pragma unroll
            for (int i = 0; i < 2; ++i) {
                int row = wr * 32 + i * 16 + (lane & 15);
                a[i] = *(const short8*)&As[row * 128 + ((kg ^ (row & 7)) << 3)];
            }
            #pragma unroll
            for (int j = 0; j < 2; ++j) {
                int row = wc * 32 + j * 16 + (lane & 15);
                b[j] = *(const short8*)&Bs[row * 128 + ((kg ^ (row & 7)) << 3)];
            }
            #pragma unroll
            for (int i = 0; i < 2; ++i)
                #pragma unroll
                for (int j = 0; j < 2; ++j)
                    acc[i][j] = __builtin_amdgcn_mfma_f32_16x16x32_bf16(a[i], b[j], acc[i][j], 0, 0, 0);
        }
        __syncthreads();
    }

    #pragma unroll
    for (int i = 0; i < 2; ++i)
        #pragma unroll
        for (int j = 0; j < 2; ++j)
            #pragma unroll
            for (int r = 0; r < 4; ++r) {
                int row = b0 + wr * 32 + i * 16 + ((lane >> 4) << 2) + r;
                int u   = u0 + wc * 32 + j * 16 + (lane & 15);
                out[(size_t)row * 2048 + OFF + u * d + mi] = acc[i][j][r];
            }
}

// ---------------------------------------------------------------------------
extern "C" void kernel_launch(void* const* d_in, const int* in_sizes, int n_in,
                              void* d_out, int out_size, void* d_ws, size_t ws_size,
                              hipStream_t stream) {
    const float* x1   = (const float*)d_in[0];
    const float* x2   = (const float*)d_in[1];
    const float* W1   = (const float*)d_in[2];
    const float* W2   = (const float*)d_in[3];
    const float* Wout = (const float*)d_in[4];
    float* out = (float*)d_out;

    prep_kernel<<<B_N + 768, 256, 0, stream>>>(x1, x2, W1, W2, Wout, out);
    gemm_c_kernel<<<4608, 256, 0, stream>>>();
    middle_kernel<<<1024, 256, 0, stream>>>();
    out_gemm_kernel<<<576, 256, 0, stream>>>(out);
}